// Round 8
// baseline (922.489 us; speedup 1.0000x reference)
//
#include <hip/hip_runtime.h>
#include <math.h>

// SSMInterBlock fused v5: d_ws elimination.
// Evidence chain: v1 (weights from d_in) -> FETCH 18 MB, WRITE 98 MB.
// v2/v3/v4 (weights from d_ws) -> FETCH 312-800 MB (= full weight set per
// block, zero L2 reuse despite 264 KB working set), WRITE ~576-600 MB,
// VGPR=64 chosen under a 128 budget (allocator not spilling). The only
// constant in the high-traffic kernels is d_ws reads -> workspace memory
// appears L2-uncached (fine-grained alloc for capture safety). v5 reads all
// weights straight from d_in: w_in/w_out/x_proj rows are contiguous per
// lane-owned output element, so no transpose is needed (per-lane float4
// row-streaming, quad-shared cache lines, L2-resident). No prep kernel.

#define THREADS 256
#define SEQ_PB  4
#define DM      96
#define DE      192
#define NJ      384
#define NST     16
#define RNK     6
#define XZS     1540   // per-seq pitch in s_xz (floats)
#define XDS     164    // per-seq pitch of x_dbl (floats)

__device__ __forceinline__ float softplus_f(float x) {
    return fmaxf(x, 0.f) + log1pf(__expf(-fabsf(x)));
}
__device__ __forceinline__ float silu_f(float x) {
    return x / (1.f + __expf(-x));
}
__device__ __forceinline__ float4 fma4(float w, float4 x, float4 a) {
    a.x = fmaf(w, x.x, a.x); a.y = fmaf(w, x.y, a.y);
    a.z = fmaf(w, x.z, a.z); a.w = fmaf(w, x.w, a.w);
    return a;
}

__global__ __launch_bounds__(THREADS, 4)
void ssm_fused5(const float* __restrict__ x,       // [nseq][384] = [seq][d][l]
                const float* __restrict__ w_in,    // [384][96]  row j contiguous
                const float* __restrict__ w_xp,    // [38][192]  row c contiguous
                const float* __restrict__ w_dt,    // [192][6]
                const float* __restrict__ b_dt,    // [192]
                const float* __restrict__ a_logs,  // [192][16]
                const float* __restrict__ dvec,    // [192]
                const float* __restrict__ gamma_,  // [192]
                const float* __restrict__ beta_,   // [192]
                const float* __restrict__ w_out,   // [96][192]  row dd contiguous
                float* __restrict__ out)           // [nseq][384] = [seq][dd][l]
{
    __shared__ float s_xz[SEQ_PB * XZS];   // 24,640 B: u|z, then y, then yz
    __shared__ float s_xd[SEQ_PB * XDS];   //  2,624 B: x_dbl
    __shared__ float s_st[32];             //    128 B: LN mu/rstd

    const int tid  = threadIdx.x;
    const int lane = tid & 63;
    const int blk  = blockIdx.x;
    const int wv   = __builtin_amdgcn_readfirstlane(tid >> 6);  // wave id = seq

    // ---------- P-A: xz = silu(x @ W1^T). wave=seq; lane owns j = m*64+lane.
    // Weights: per-lane float4 row chunks of w_in[j][dd..dd+3] (row-major, no
    // transpose needed). x via wave-uniform pointer -> s_loads. No LDS here.
    {
        const float4* xs4 = (const float4*)(x + ((size_t)blk * SEQ_PB + wv) * NJ);
        const float* wl0 = w_in + lane * DM;     // j = lane (m=0); +m*6144 floats
        float4 zero4 = make_float4(0.f, 0.f, 0.f, 0.f);
        float4 acc0 = zero4, acc1 = zero4, acc2 = zero4;
        float4 acc3 = zero4, acc4 = zero4, acc5 = zero4;
        #pragma unroll 1
        for (int ddq = 0; ddq < DM / 4; ++ddq) {
            float4 xv0 = xs4[4 * ddq + 0];       // uniform -> s_load
            float4 xv1 = xs4[4 * ddq + 1];
            float4 xv2 = xs4[4 * ddq + 2];
            float4 xv3 = xs4[4 * ddq + 3];
            const float* wp = wl0 + 4 * ddq;
            float4 w0 = *(const float4*)(wp + 0 * 64 * DM);
            float4 w1 = *(const float4*)(wp + 1 * 64 * DM);
            float4 w2 = *(const float4*)(wp + 2 * 64 * DM);
            float4 w3 = *(const float4*)(wp + 3 * 64 * DM);
            float4 w4 = *(const float4*)(wp + 4 * 64 * DM);
            float4 w5 = *(const float4*)(wp + 5 * 64 * DM);
            acc0 = fma4(w0.x, xv0, acc0); acc0 = fma4(w0.y, xv1, acc0);
            acc0 = fma4(w0.z, xv2, acc0); acc0 = fma4(w0.w, xv3, acc0);
            acc1 = fma4(w1.x, xv0, acc1); acc1 = fma4(w1.y, xv1, acc1);
            acc1 = fma4(w1.z, xv2, acc1); acc1 = fma4(w1.w, xv3, acc1);
            acc2 = fma4(w2.x, xv0, acc2); acc2 = fma4(w2.y, xv1, acc2);
            acc2 = fma4(w2.z, xv2, acc2); acc2 = fma4(w2.w, xv3, acc2);
            acc3 = fma4(w3.x, xv0, acc3); acc3 = fma4(w3.y, xv1, acc3);
            acc3 = fma4(w3.z, xv2, acc3); acc3 = fma4(w3.w, xv3, acc3);
            acc4 = fma4(w4.x, xv0, acc4); acc4 = fma4(w4.y, xv1, acc4);
            acc4 = fma4(w4.z, xv2, acc4); acc4 = fma4(w4.w, xv3, acc4);
            acc5 = fma4(w5.x, xv0, acc5); acc5 = fma4(w5.y, xv1, acc5);
            acc5 = fma4(w5.z, xv2, acc5); acc5 = fma4(w5.w, xv3, acc5);
        }
#define PA_OUT(ACC, M) { \
        float4 sv_; \
        sv_.x = silu_f(ACC.x); sv_.y = silu_f(ACC.y); \
        sv_.z = silu_f(ACC.z); sv_.w = silu_f(ACC.w); \
        *(float4*)&s_xz[wv * XZS + ((M) * 64 + lane) * 4] = sv_; }
        PA_OUT(acc0, 0) PA_OUT(acc1, 1) PA_OUT(acc2, 2)
        PA_OUT(acc3, 3) PA_OUT(acc4, 4) PA_OUT(acc5, 5)
#undef PA_OUT
    }
    __syncthreads();

    // ---------- P-B: x_dbl[c][l] = sum_d u[d][l] * w_xp[c][d]; row c contiguous
    if (tid < SEQ_PB * (RNK + 2 * NST)) {
        int seq = tid & 3, c = tid >> 2;
        const float* wc = w_xp + c * DE;              // row-major, quad-shared line
        const float* uz = &s_xz[seq * XZS];
        float4 a4 = make_float4(0.f, 0.f, 0.f, 0.f);
        #pragma unroll 1
        for (int dq = 0; dq < DE / 4; ++dq) {
            float4 wq = *(const float4*)&wc[dq * 4];
            float4 u0 = *(const float4*)&uz[(dq * 4 + 0) * 4];
            float4 u1 = *(const float4*)&uz[(dq * 4 + 1) * 4];
            float4 u2 = *(const float4*)&uz[(dq * 4 + 2) * 4];
            float4 u3 = *(const float4*)&uz[(dq * 4 + 3) * 4];
            a4 = fma4(wq.x, u0, a4); a4 = fma4(wq.y, u1, a4);
            a4 = fma4(wq.z, u2, a4); a4 = fma4(wq.w, u3, a4);
        }
        *(float4*)&s_xd[seq * XDS + c * 4] = a4;
    }
    __syncthreads();

    // ---------- P-C: delta + selective scan (n outer, h scalar); y in place
    #pragma unroll 1
    for (int rr = 0; rr < 3; ++rr) {
        int p = tid + rr * THREADS;
        int seq = p & 3, d = p >> 2;
        float4 u4 = *(const float4*)&s_xz[seq * XZS + d * 4];
        const float* xd = &s_xd[seq * XDS];

        const float2* wdt2 = (const float2*)(w_dt + d * RNK);  // 8B-aligned
        float2 wp0 = wdt2[0], wp1 = wdt2[1], wp2 = wdt2[2];
        float d0, d1, d2, d3;
        {
            float4 t0 = *(const float4*)&xd[0];
            float4 t1 = *(const float4*)&xd[4];
            float4 t2 = *(const float4*)&xd[8];
            float4 t3 = *(const float4*)&xd[12];
            float4 t4 = *(const float4*)&xd[16];
            float4 t5 = *(const float4*)&xd[20];
            d0 = wp0.x * t0.x; d1 = wp0.x * t0.y; d2 = wp0.x * t0.z; d3 = wp0.x * t0.w;
            d0 = fmaf(wp0.y, t1.x, d0); d1 = fmaf(wp0.y, t1.y, d1);
            d2 = fmaf(wp0.y, t1.z, d2); d3 = fmaf(wp0.y, t1.w, d3);
            d0 = fmaf(wp1.x, t2.x, d0); d1 = fmaf(wp1.x, t2.y, d1);
            d2 = fmaf(wp1.x, t2.z, d2); d3 = fmaf(wp1.x, t2.w, d3);
            d0 = fmaf(wp1.y, t3.x, d0); d1 = fmaf(wp1.y, t3.y, d1);
            d2 = fmaf(wp1.y, t3.z, d2); d3 = fmaf(wp1.y, t3.w, d3);
            d0 = fmaf(wp2.x, t4.x, d0); d1 = fmaf(wp2.x, t4.y, d1);
            d2 = fmaf(wp2.x, t4.z, d2); d3 = fmaf(wp2.x, t4.w, d3);
            d0 = fmaf(wp2.y, t5.x, d0); d1 = fmaf(wp2.y, t5.y, d1);
            d2 = fmaf(wp2.y, t5.z, d2); d3 = fmaf(wp2.y, t5.w, d3);
        }
        float bias = b_dt[d];
        float dl0 = softplus_f(d0 + bias), dl1 = softplus_f(d1 + bias);
        float dl2 = softplus_f(d2 + bias), dl3 = softplus_f(d3 + bias);
        float du0 = dl0 * u4.x, du1 = dl1 * u4.y;
        float du2 = dl2 * u4.z, du3 = dl3 * u4.w;

        const float* ap = a_logs + d * NST;           // quad-shared 64B line
        float y0 = 0.f, y1 = 0.f, y2 = 0.f, y3 = 0.f;
        #pragma unroll
        for (int n = 0; n < NST; ++n) {
            float an = -__expf(ap[n]);                // A = -exp(A_logs)
            float4 bn = *(const float4*)&xd[(RNK + n) * 4];
            float4 cn = *(const float4*)&xd[(RNK + NST + n) * 4];
            float h = du0 * bn.x;                        // l=0
            y0 = fmaf(h, cn.x, y0);
            h = fmaf(du1, bn.y, __expf(dl1 * an) * h);   // l=1
            y1 = fmaf(h, cn.y, y1);
            h = fmaf(du2, bn.z, __expf(dl2 * an) * h);   // l=2
            y2 = fmaf(h, cn.z, y2);
            h = fmaf(du3, bn.w, __expf(dl3 * an) * h);   // l=3
            y3 = fmaf(h, cn.w, y3);
        }
        float Dd = dvec[d];
        float4 yo;
        yo.x = fmaf(Dd, u4.x, y0); yo.y = fmaf(Dd, u4.y, y1);
        yo.z = fmaf(Dd, u4.z, y2); yo.w = fmaf(Dd, u4.w, y3);
        *(float4*)&s_xz[seq * XZS + d * 4] = yo;
    }
    __syncthreads();

    // ---------- P-LN: per (seq,l) mean/rstd over De=192
    {
        int g = tid >> 4, i = tid & 15;
        int seq = g >> 2, l = g & 3;
        float s = 0.f, ss = 0.f;
        #pragma unroll
        for (int k = 0; k < DE / 16; ++k) {
            float v = s_xz[seq * XZS + (i + k * 16) * 4 + l];
            s += v; ss = fmaf(v, v, ss);
        }
        #pragma unroll
        for (int off = 1; off < 16; off <<= 1) {
            s  += __shfl_xor(s,  off, 16);
            ss += __shfl_xor(ss, off, 16);
        }
        if (i == 0) {
            float mu  = s * (1.f / DE);
            float var = ss * (1.f / DE) - mu * mu;
            s_st[g]      = mu;
            s_st[16 + g] = rsqrtf(var + 1e-5f);
        }
    }
    __syncthreads();

    // ---------- P-LN2: yz = ((y-mu)*rstd*gamma + beta) * z, in place
    #pragma unroll 1
    for (int rr = 0; rr < 3; ++rr) {
        int p = tid + rr * THREADS;
        int seq = p & 3, d = p >> 2;
        float4 y4  = *(const float4*)&s_xz[seq * XZS + d * 4];
        float4 z4  = *(const float4*)&s_xz[seq * XZS + (DE + d) * 4];
        float4 mu4 = *(const float4*)&s_st[seq * 4];
        float4 rs4 = *(const float4*)&s_st[16 + seq * 4];
        float ga = gamma_[d], be = beta_[d];
        float4 o;
        o.x = fmaf((y4.x - mu4.x) * rs4.x, ga, be) * z4.x;
        o.y = fmaf((y4.y - mu4.y) * rs4.y, ga, be) * z4.y;
        o.z = fmaf((y4.z - mu4.z) * rs4.z, ga, be) * z4.z;
        o.w = fmaf((y4.w - mu4.w) * rs4.w, ga, be) * z4.w;
        *(float4*)&s_xz[seq * XZS + d * 4] = o;
    }
    __syncthreads();

    // ---------- P-D: out[dd][l] = sum_d yz[d][l] * w_out[dd][d]; wave=seq.
    // w_out row dd contiguous -> per-lane float4 row streaming.
    {
        const int dd1 = lane;              // 0..63
        const int dd2 = 64 + (lane & 31);  // 64..95 (upper half duplicates, masked store)
        const float* wr1 = w_out + dd1 * DE;
        const float* wr2 = w_out + dd2 * DE;
        const float* yzp = &s_xz[wv * XZS];
        float4 o1 = make_float4(0.f, 0.f, 0.f, 0.f);
        float4 o2 = make_float4(0.f, 0.f, 0.f, 0.f);
        #pragma unroll 1
        for (int dq = 0; dq < DE / 4; ++dq) {
            int d = dq * 4;
            float4 w1q = *(const float4*)&wr1[d];
            float4 w2q = *(const float4*)&wr2[d];
            float4 yz0 = *(const float4*)&yzp[(d + 0) * 4];   // broadcast b128
            float4 yz1 = *(const float4*)&yzp[(d + 1) * 4];
            float4 yz2 = *(const float4*)&yzp[(d + 2) * 4];
            float4 yz3 = *(const float4*)&yzp[(d + 3) * 4];
            o1 = fma4(w1q.x, yz0, o1); o1 = fma4(w1q.y, yz1, o1);
            o1 = fma4(w1q.z, yz2, o1); o1 = fma4(w1q.w, yz3, o1);
            o2 = fma4(w2q.x, yz0, o2); o2 = fma4(w2q.y, yz1, o2);
            o2 = fma4(w2q.z, yz2, o2); o2 = fma4(w2q.w, yz3, o2);
        }
        float* ob = out + (size_t)blk * (SEQ_PB * NJ) + wv * NJ;
        *(float4*)&ob[dd1 * 4] = o1;
        if (lane < 32)
            *(float4*)&ob[dd2 * 4] = o2;
    }
}

extern "C" void kernel_launch(void* const* d_in, const int* in_sizes, int n_in,
                              void* d_out, int out_size, void* d_ws, size_t ws_size,
                              hipStream_t stream) {
    (void)n_in; (void)d_ws; (void)ws_size; (void)out_size;
    int nseq = in_sizes[0] / NJ;            // 12544 = 4*56*56
    int grid = nseq / SEQ_PB;               // 3136 blocks
    if (grid < 1) grid = 1;
    ssm_fused5<<<grid, THREADS, 0, stream>>>(
        (const float*)d_in[0],  // x
        (const float*)d_in[1],  // in_proj_w
        (const float*)d_in[2],  // x_proj_weight
        (const float*)d_in[3],  // dt_projs_weight
        (const float*)d_in[4],  // dt_projs_bias
        (const float*)d_in[5],  // A_logs
        (const float*)d_in[6],  // Ds
        (const float*)d_in[7],  // ln_gamma
        (const float*)d_in[8],  // ln_beta
        (const float*)d_in[9],  // out_proj_w
        (float*)d_out);
}

// Round 9
// 445.946 us; speedup vs baseline: 2.0686x; 2.0686x over previous
//
#include <hip/hip_runtime.h>
#include <math.h>

// SSMInterBlock fused v6: VMEM-issue reduction.
// Evidence: v2 (coalesced b32 weights) 348us beats v1/v3/v4/v5; all global-weight
// versions VMEM-latency bound (VALUBusy 26-37%, 576 weight loads/wave in P-A);
// v5 proved per-lane row gathers are poison; TCC FETCH/WRITE invariant ~600MB
// across disjoint designs -> attribution artifact, optimize dur_us only.
// v6: P-A lane owns a j-QUAD -> b128 coalesced weight loads (96x2 VMEM/wave vs
// 96x6), x on scalar pipe; s_u is l-major so P-A stores are lane-consecutive
// b128; scan writes d-major s_yz for P-D's broadcast reads. Math per v5 (verified).

#define THREADS 256
#define SEQ_PB  4
#define DM      96
#define DE      192
#define NJ      384
#define NST     16
#define RNK     6
#define NC      38
#define DP      388            // l-row pitch in s_u (u 0..191, z 192..383, +4 pad)
#define SUP     (4 * DP)       // 1552 floats per seq
#define YP      776            // s_yz per-seq pitch (192*4 + 8 stagger)
#define XDS     164            // x_dbl per-seq pitch

#define OFF_W1T 0              // ws: [96][384]  w1t[dd][j] = w_in[j][dd]
#define OFF_WO  36864          // ws: [192][96]  wo[d][dd]  = w_out[dd][d]

__device__ __forceinline__ float softplus_f(float x) {
    return fmaxf(x, 0.f) + log1pf(__expf(-fabsf(x)));
}
__device__ __forceinline__ float silu_f(float x) {
    return x / (1.f + __expf(-x));
}
__device__ __forceinline__ float4 fma4(float w, float4 x, float4 a) {
    a.x = fmaf(w, x.x, a.x); a.y = fmaf(w, x.y, a.y);
    a.z = fmaf(w, x.z, a.z); a.w = fmaf(w, x.w, a.w);
    return a;
}
__device__ __forceinline__ float dot4acc(float4 w, float4 u, float a) {
    a = fmaf(w.x, u.x, a); a = fmaf(w.y, u.y, a);
    a = fmaf(w.z, u.z, a); a = fmaf(w.w, u.w, a);
    return a;
}
__device__ __forceinline__ float4 silu4(float4 v) {
    v.x = silu_f(v.x); v.y = silu_f(v.y); v.z = silu_f(v.z); v.w = silu_f(v.w);
    return v;
}

__global__ void prep_weights(const float* __restrict__ w_in,
                             const float* __restrict__ w_out,
                             float* __restrict__ ws) {
    int t0 = blockIdx.x * blockDim.x + threadIdx.x;
    int stride = gridDim.x * blockDim.x;
    for (int t = t0; t < DM * NJ; t += stride) {          // W1^T [dd][j]
        int dd = t / NJ, j = t % NJ;
        ws[OFF_W1T + t] = w_in[j * DM + dd];
    }
    for (int t = t0; t < DE * DM; t += stride) {          // Wout^T [d][dd]
        int d = t / DM, dd = t % DM;
        ws[OFF_WO + t] = w_out[dd * DE + d];
    }
}

__global__ __launch_bounds__(THREADS, 4)
void ssm_fused6(const float* __restrict__ x,       // [nseq][384] = [seq][d][l]
                const float* __restrict__ w_xp,    // [38][192] row c contiguous
                const float* __restrict__ w_dt,    // [192][6]
                const float* __restrict__ b_dt,    // [192]
                const float* __restrict__ a_logs,  // [192][16]
                const float* __restrict__ dvec,    // [192]
                const float* __restrict__ gamma_,  // [192]
                const float* __restrict__ beta_,   // [192]
                const float* __restrict__ ws,      // W1^T | Wout^T
                float* __restrict__ out)           // [nseq][384] = [seq][dd][l]
{
    __shared__ float s_u[SEQ_PB * SUP];    // 24,832 B: l-major u|z rows
    __shared__ float s_yz[SEQ_PB * YP];    // 12,416 B: d-major y, then yz
    __shared__ float s_xd[SEQ_PB * XDS];   //  2,624 B: x_dbl [c][l] quads
    __shared__ float s_st[32];             //    128 B: LN mu/rstd

    const int tid  = threadIdx.x;
    const int lane = tid & 63;
    const int blk  = blockIdx.x;
    const int wv   = __builtin_amdgcn_readfirstlane(tid >> 6);  // wave = seq

    // ---------- P-A: xz = silu(x @ W1^T). Lane owns j-quads {4*lane..4*lane+3}
    // and {256+4*(lane&31)..} (upper half duplicates, store masked).
    // Weights: b128 lane-consecutive (1KB/inst). x: wave-uniform s_loads.
    {
        const float4* xs4 = (const float4*)(x + ((size_t)blk * SEQ_PB + wv) * NJ);
        const float* wa_base = ws + OFF_W1T + 4 * lane;
        const float* wb_base = ws + OFF_W1T + 256 + 4 * (lane & 31);
        float4 z4 = make_float4(0.f, 0.f, 0.f, 0.f);
        float4 a0 = z4, a1 = z4, a2 = z4, a3 = z4;   // ja quads, f4 over l
        float4 b0 = z4, b1 = z4, b2 = z4, b3 = z4;   // jb quads
        #pragma unroll 4
        for (int dd = 0; dd < DM; ++dd) {
            float4 xv = xs4[dd];                                  // s_load
            float4 wa = *(const float4*)(wa_base + dd * NJ);      // b128 coalesced
            float4 wb = *(const float4*)(wb_base + dd * NJ);
            a0 = fma4(wa.x, xv, a0); a1 = fma4(wa.y, xv, a1);
            a2 = fma4(wa.z, xv, a2); a3 = fma4(wa.w, xv, a3);
            b0 = fma4(wb.x, xv, b0); b1 = fma4(wb.y, xv, b1);
            b2 = fma4(wb.z, xv, b2); b3 = fma4(wb.w, xv, b3);
        }
        float* su = s_u + wv * SUP;
        // l-major stores: row l, columns j.. lane-consecutive b128 (conflict-free)
        *(float4*)&su[0 * DP + 4 * lane] = silu4(make_float4(a0.x, a1.x, a2.x, a3.x));
        *(float4*)&su[1 * DP + 4 * lane] = silu4(make_float4(a0.y, a1.y, a2.y, a3.y));
        *(float4*)&su[2 * DP + 4 * lane] = silu4(make_float4(a0.z, a1.z, a2.z, a3.z));
        *(float4*)&su[3 * DP + 4 * lane] = silu4(make_float4(a0.w, a1.w, a2.w, a3.w));
        if (lane < 32) {
            *(float4*)&su[0 * DP + 256 + 4 * lane] = silu4(make_float4(b0.x, b1.x, b2.x, b3.x));
            *(float4*)&su[1 * DP + 256 + 4 * lane] = silu4(make_float4(b0.y, b1.y, b2.y, b3.y));
            *(float4*)&su[2 * DP + 256 + 4 * lane] = silu4(make_float4(b0.z, b1.z, b2.z, b3.z));
            *(float4*)&su[3 * DP + 256 + 4 * lane] = silu4(make_float4(b0.w, b1.w, b2.w, b3.w));
        }
    }
    __syncthreads();

    // ---------- P-B: x_dbl[c][l] = sum_d u[d][l] * w_xp[c][d]
    if (tid < SEQ_PB * NC) {
        int seq = tid & 3, c = tid >> 2;
        const float* wc = w_xp + c * DE;             // row c, b128 quad-shared
        const float* su = s_u + seq * SUP;
        float c0 = 0.f, c1 = 0.f, c2 = 0.f, c3 = 0.f;
        #pragma unroll 4
        for (int dq = 0; dq < DE / 4; ++dq) {
            float4 wq = *(const float4*)&wc[4 * dq];
            float4 u0 = *(const float4*)&su[0 * DP + 4 * dq];
            float4 u1 = *(const float4*)&su[1 * DP + 4 * dq];
            float4 u2 = *(const float4*)&su[2 * DP + 4 * dq];
            float4 u3 = *(const float4*)&su[3 * DP + 4 * dq];
            c0 = dot4acc(wq, u0, c0);
            c1 = dot4acc(wq, u1, c1);
            c2 = dot4acc(wq, u2, c2);
            c3 = dot4acc(wq, u3, c3);
        }
        *(float4*)&s_xd[seq * XDS + c * 4] = make_float4(c0, c1, c2, c3);
    }
    __syncthreads();

    // ---------- P-C: delta + selective scan; y -> d-major s_yz
    #pragma unroll 1
    for (int rr = 0; rr < 3; ++rr) {
        int p = tid + rr * THREADS;
        int seq = p & 3, d = p >> 2;
        const float* su = s_u + seq * SUP;
        float u0 = su[0 * DP + d], u1 = su[1 * DP + d];
        float u2 = su[2 * DP + d], u3 = su[3 * DP + d];
        const float* xd = &s_xd[seq * XDS];

        const float2* wdt2 = (const float2*)(w_dt + d * RNK);
        float2 wp0 = wdt2[0], wp1 = wdt2[1], wp2 = wdt2[2];
        float d0, d1, d2, d3;
        {
            float4 t0 = *(const float4*)&xd[0];
            float4 t1 = *(const float4*)&xd[4];
            float4 t2 = *(const float4*)&xd[8];
            float4 t3 = *(const float4*)&xd[12];
            float4 t4 = *(const float4*)&xd[16];
            float4 t5 = *(const float4*)&xd[20];
            d0 = wp0.x * t0.x; d1 = wp0.x * t0.y; d2 = wp0.x * t0.z; d3 = wp0.x * t0.w;
            d0 = fmaf(wp0.y, t1.x, d0); d1 = fmaf(wp0.y, t1.y, d1);
            d2 = fmaf(wp0.y, t1.z, d2); d3 = fmaf(wp0.y, t1.w, d3);
            d0 = fmaf(wp1.x, t2.x, d0); d1 = fmaf(wp1.x, t2.y, d1);
            d2 = fmaf(wp1.x, t2.z, d2); d3 = fmaf(wp1.x, t2.w, d3);
            d0 = fmaf(wp1.y, t3.x, d0); d1 = fmaf(wp1.y, t3.y, d1);
            d2 = fmaf(wp1.y, t3.z, d2); d3 = fmaf(wp1.y, t3.w, d3);
            d0 = fmaf(wp2.x, t4.x, d0); d1 = fmaf(wp2.x, t4.y, d1);
            d2 = fmaf(wp2.x, t4.z, d2); d3 = fmaf(wp2.x, t4.w, d3);
            d0 = fmaf(wp2.y, t5.x, d0); d1 = fmaf(wp2.y, t5.y, d1);
            d2 = fmaf(wp2.y, t5.z, d2); d3 = fmaf(wp2.y, t5.w, d3);
        }
        float bias = b_dt[d];
        float dl0 = softplus_f(d0 + bias), dl1 = softplus_f(d1 + bias);
        float dl2 = softplus_f(d2 + bias), dl3 = softplus_f(d3 + bias);
        float du0 = dl0 * u0, du1 = dl1 * u1;
        float du2 = dl2 * u2, du3 = dl3 * u3;

        const float* ap = a_logs + d * NST;
        float y0 = 0.f, y1 = 0.f, y2 = 0.f, y3 = 0.f;
        #pragma unroll
        for (int n = 0; n < NST; ++n) {
            float an = -__expf(ap[n]);                   // A = -exp(A_logs)
            float4 bn = *(const float4*)&xd[(RNK + n) * 4];
            float4 cn = *(const float4*)&xd[(RNK + NST + n) * 4];
            float h = du0 * bn.x;                        // l=0 (h_prev = 0)
            y0 = fmaf(h, cn.x, y0);
            h = fmaf(du1, bn.y, __expf(dl1 * an) * h);   // l=1
            y1 = fmaf(h, cn.y, y1);
            h = fmaf(du2, bn.z, __expf(dl2 * an) * h);   // l=2
            y2 = fmaf(h, cn.z, y2);
            h = fmaf(du3, bn.w, __expf(dl3 * an) * h);   // l=3
            y3 = fmaf(h, cn.w, y3);
        }
        float Dd = dvec[d];
        float4 yo;
        yo.x = fmaf(Dd, u0, y0); yo.y = fmaf(Dd, u1, y1);
        yo.z = fmaf(Dd, u2, y2); yo.w = fmaf(Dd, u3, y3);
        *(float4*)&s_yz[seq * YP + d * 4] = yo;          // d-major, lane-consecutive
    }
    __syncthreads();

    // ---------- P-LN: per (seq,l) mean/rstd over De=192
    {
        int g = tid >> 4, i = tid & 15;
        int seq = g >> 2, l = g & 3;
        float s = 0.f, ss = 0.f;
        #pragma unroll
        for (int k = 0; k < DE / 16; ++k) {
            float v = s_yz[seq * YP + (i + k * 16) * 4 + l];
            s += v; ss = fmaf(v, v, ss);
        }
        #pragma unroll
        for (int off = 1; off < 16; off <<= 1) {
            s  += __shfl_xor(s,  off, 16);
            ss += __shfl_xor(ss, off, 16);
        }
        if (i == 0) {
            float mu  = s * (1.f / DE);
            float var = ss * (1.f / DE) - mu * mu;
            s_st[g]      = mu;
            s_st[16 + g] = rsqrtf(var + 1e-5f);
        }
    }
    __syncthreads();

    // ---------- P-LN2: yz = ((y-mu)*rstd*gamma + beta) * z, in s_yz
    #pragma unroll 1
    for (int rr = 0; rr < 3; ++rr) {
        int p = tid + rr * THREADS;
        int seq = p & 3, d = p >> 2;
        float4 y4 = *(const float4*)&s_yz[seq * YP + d * 4];
        const float* su = s_u + seq * SUP;
        float z0 = su[0 * DP + DE + d], z1 = su[1 * DP + DE + d];
        float z2 = su[2 * DP + DE + d], z3 = su[3 * DP + DE + d];
        float4 mu4 = *(const float4*)&s_st[seq * 4];
        float4 rs4 = *(const float4*)&s_st[16 + seq * 4];
        float ga = gamma_[d], be = beta_[d];
        float4 o;
        o.x = fmaf((y4.x - mu4.x) * rs4.x, ga, be) * z0;
        o.y = fmaf((y4.y - mu4.y) * rs4.y, ga, be) * z1;
        o.z = fmaf((y4.z - mu4.z) * rs4.z, ga, be) * z2;
        o.w = fmaf((y4.w - mu4.w) * rs4.w, ga, be) * z3;
        *(float4*)&s_yz[seq * YP + d * 4] = o;
    }
    __syncthreads();

    // ---------- P-D: out[dd][l] = sum_d yz[d][l] * wo[d][dd]; wave=seq
    {
        const int dd1 = lane;              // 0..63
        const int dd2 = 64 + (lane & 31);  // 64..95 (upper dup, masked store)
        const float* wo  = ws + OFF_WO;
        const float* yzp = s_yz + wv * YP;
        float4 o1 = make_float4(0.f, 0.f, 0.f, 0.f);
        float4 o2 = make_float4(0.f, 0.f, 0.f, 0.f);
        #pragma unroll 4
        for (int d = 0; d < DE; ++d) {
            float4 yz = *(const float4*)&yzp[d * 4];     // b128 broadcast
            float w1 = wo[d * DM + dd1];                 // b32 coalesced
            float w2 = wo[d * DM + dd2];
            o1 = fma4(w1, yz, o1);
            o2 = fma4(w2, yz, o2);
        }
        float* ob = out + (size_t)blk * (SEQ_PB * NJ) + wv * NJ;
        *(float4*)&ob[4 * dd1] = o1;
        if (lane < 32)
            *(float4*)&ob[4 * dd2] = o2;
    }
}

extern "C" void kernel_launch(void* const* d_in, const int* in_sizes, int n_in,
                              void* d_out, int out_size, void* d_ws, size_t ws_size,
                              hipStream_t stream) {
    (void)n_in; (void)ws_size; (void)out_size;
    int nseq = in_sizes[0] / NJ;            // 12544 = 4*56*56
    int grid = nseq / SEQ_PB;               // 3136 blocks
    if (grid < 1) grid = 1;
    float* ws = (float*)d_ws;               // 221 KB used

    prep_weights<<<64, THREADS, 0, stream>>>(
        (const float*)d_in[1],  // in_proj_w
        (const float*)d_in[9],  // out_proj_w
        ws);

    ssm_fused6<<<grid, THREADS, 0, stream>>>(
        (const float*)d_in[0],  // x
        (const float*)d_in[2],  // x_proj_weight
        (const float*)d_in[3],  // dt_projs_weight
        (const float*)d_in[4],  // dt_projs_bias
        (const float*)d_in[5],  // A_logs
        (const float*)d_in[6],  // Ds
        (const float*)d_in[7],  // ln_gamma
        (const float*)d_in[8],  // ln_beta
        ws,
        (float*)d_out);
}

// Round 10
// 334.809 us; speedup vs baseline: 2.7553x; 1.3319x over previous
//
#include <hip/hip_runtime.h>
#include <math.h>

// SSMInterBlock fused v7: barrier-free wave-independent execution.
// Evidence R3-R9: all barriered versions stuck 348-900us at VALUBusy ~37%
// (63% stall: phase convoys at 7 __syncthreads expose every phase's latency);
// TCC FETCH/WRITE proven artifact (WRITE bit-identical across disjoint kernels).
// v7: one wave = one sequence; per-wave private LDS region; intra-wave DS
// ordering replaces all barriers -> 16-24 independent waves/CU overlap freely.
// u,z,y live in registers across phases (P-A column ownership == scan/LN2 d
// ownership); LN via 64-lane shuffles; -exp(A_logs)/w_dt transposed in prep
// for coalesced b32. P-A = v2's proven b32-coalesced weight pattern.

#define THREADS 256
#define SEQ_PB  4
#define DM      96
#define DE      192
#define NJ      384
#define NST     16
#define RNK     6
#define NC      38

#define WP      1692           // per-wave LDS region pitch (floats)
#define SU_OFF  0              // u d-major quads [d*4+l], 768 f
#define XD_OFF  768            // x_dbl quads [c*4+l], 152 f
#define YZ_OFF  920            // yz d-major quads, 768 f (total 1688 <= WP)

// ws float offsets
#define OFF_W1T 0              // [96][384]  w1t[dd][j] = w_in[j][dd]
#define OFF_WO  36864          // [192][96]  wo[d][dd]  = w_out[dd][d]
#define OFF_NAT 55296          // [16][192]  nat[n][d]  = -exp(a_logs[d][n])
#define OFF_DTT 58368          // [6][192]   dtt[r][d]  = w_dt[d][r]
                               // end 59520 floats = 238,080 B

__device__ __forceinline__ float softplus_f(float x) {
    return fmaxf(x, 0.f) + log1pf(__expf(-fabsf(x)));
}
__device__ __forceinline__ float silu_f(float x) {
    return x / (1.f + __expf(-x));
}
__device__ __forceinline__ float4 silu4(float4 v) {
    v.x = silu_f(v.x); v.y = silu_f(v.y); v.z = silu_f(v.z); v.w = silu_f(v.w);
    return v;
}
__device__ __forceinline__ float4 fma4(float w, float4 x, float4 a) {
    a.x = fmaf(w, x.x, a.x); a.y = fmaf(w, x.y, a.y);
    a.z = fmaf(w, x.z, a.z); a.w = fmaf(w, x.w, a.w);
    return a;
}

__global__ void prep_weights(const float* __restrict__ w_in,
                             const float* __restrict__ w_out,
                             const float* __restrict__ a_logs,
                             const float* __restrict__ w_dt,
                             float* __restrict__ ws) {
    int t0 = blockIdx.x * blockDim.x + threadIdx.x;
    int stride = gridDim.x * blockDim.x;
    for (int t = t0; t < DM * NJ; t += stride) {          // W1^T
        int dd = t / NJ, j = t % NJ;
        ws[OFF_W1T + t] = w_in[j * DM + dd];
    }
    for (int t = t0; t < DE * DM; t += stride) {          // Wout^T
        int d = t / DM, dd = t % DM;
        ws[OFF_WO + t] = w_out[dd * DE + d];
    }
    for (int t = t0; t < NST * DE; t += stride) {         // -exp(A_logs)^T
        int n = t / DE, d = t % DE;
        ws[OFF_NAT + t] = -__expf(a_logs[d * NST + n]);
    }
    for (int t = t0; t < RNK * DE; t += stride) {         // w_dt^T
        int r = t / DE, d = t % DE;
        ws[OFF_DTT + t] = w_dt[d * RNK + r];
    }
}

__global__ __launch_bounds__(THREADS, 4)
void ssm_fused7(const float* __restrict__ x,       // [nseq][384] = [seq][d][l]
                const float* __restrict__ w_xp,    // [38][192] row c contiguous
                const float* __restrict__ b_dt,    // [192]
                const float* __restrict__ dvec,    // [192]
                const float* __restrict__ gamma_,  // [192]
                const float* __restrict__ beta_,   // [192]
                const float* __restrict__ ws,
                float* __restrict__ out)           // [nseq][384] = [seq][dd][l]
{
    __shared__ float lds[SEQ_PB * WP];   // 27,072 B; 4 private per-wave regions

    const int tid  = threadIdx.x;
    const int lane = tid & 63;
    const int blk  = blockIdx.x;
    const int wv   = __builtin_amdgcn_readfirstlane(tid >> 6);  // wave = seq
    float* W = lds + wv * WP;

    // ---------- P-A: xz = silu(x @ W1^T). lane owns j = lane + 64m, m=0..5.
    // Weights b32 lane-coalesced (v2 pattern); x wave-uniform -> s_loads.
    float4 u0, u1, u2, z0, z1, z2;
    {
        const float4* xs4 = (const float4*)(x + ((size_t)blk * SEQ_PB + wv) * NJ);
        const float* wb = ws + OFF_W1T + lane;
        float4 zz = make_float4(0.f, 0.f, 0.f, 0.f);
        float4 a0 = zz, a1 = zz, a2 = zz, a3 = zz, a4 = zz, a5 = zz;
        #pragma unroll 1
        for (int dds = 0; dds < DM; dds += 8) {
            float4 xv0 = xs4[dds + 0], xv1 = xs4[dds + 1];
            float4 xv2 = xs4[dds + 2], xv3 = xs4[dds + 3];
            float4 xv4 = xs4[dds + 4], xv5 = xs4[dds + 5];
            float4 xv6 = xs4[dds + 6], xv7 = xs4[dds + 7];
#define PA_I(XV, I) { \
            const float* wr_ = wb + (dds + (I)) * NJ; \
            float w_; \
            w_ = wr_[0];   a0 = fma4(w_, XV, a0); \
            w_ = wr_[64];  a1 = fma4(w_, XV, a1); \
            w_ = wr_[128]; a2 = fma4(w_, XV, a2); \
            w_ = wr_[192]; a3 = fma4(w_, XV, a3); \
            w_ = wr_[256]; a4 = fma4(w_, XV, a4); \
            w_ = wr_[320]; a5 = fma4(w_, XV, a5); }
            PA_I(xv0, 0) PA_I(xv1, 1) PA_I(xv2, 2) PA_I(xv3, 3)
            PA_I(xv4, 4) PA_I(xv5, 5) PA_I(xv6, 6) PA_I(xv7, 7)
#undef PA_I
        }
        u0 = silu4(a0); u1 = silu4(a1); u2 = silu4(a2);   // d = lane+64k
        z0 = silu4(a3); z1 = silu4(a4); z2 = silu4(a5);   // z for same d
        // u to per-wave LDS (d-major quads) for P-B's cross-d reduction
        *(float4*)&W[SU_OFF + 4 * lane]         = u0;
        *(float4*)&W[SU_OFF + 4 * (lane + 64)]  = u1;
        *(float4*)&W[SU_OFF + 4 * (lane + 128)] = u2;
    }
    // (no barrier: intra-wave DS ops are in-order)

    // ---------- P-B: x_dbl[c][l] = sum_d u[d][l] * w_xp[c][d]; c = lane < 38
    if (lane < NC) {
        const float* wc = w_xp + lane * DE;
        float4 cacc = make_float4(0.f, 0.f, 0.f, 0.f);
        #pragma unroll 4
        for (int dq = 0; dq < DE / 4; ++dq) {
            float4 wq = *(const float4*)&wc[4 * dq];
            float4 q0 = *(const float4*)&W[SU_OFF + 4 * (4 * dq + 0)];
            float4 q1 = *(const float4*)&W[SU_OFF + 4 * (4 * dq + 1)];
            float4 q2 = *(const float4*)&W[SU_OFF + 4 * (4 * dq + 2)];
            float4 q3 = *(const float4*)&W[SU_OFF + 4 * (4 * dq + 3)];
            cacc = fma4(wq.x, q0, cacc); cacc = fma4(wq.y, q1, cacc);
            cacc = fma4(wq.z, q2, cacc); cacc = fma4(wq.w, q3, cacc);
        }
        *(float4*)&W[XD_OFF + 4 * lane] = cacc;
    }

    // ---------- P-C: delta + selective scan; lane owns d = lane + 64k
    float4 y_0, y_1, y_2;
#define SCAN_K(K, U4, YOUT) { \
    const int d = lane + 64 * (K); \
    float4 t0 = *(const float4*)&W[XD_OFF + 0]; \
    float4 t1 = *(const float4*)&W[XD_OFF + 4]; \
    float4 t2 = *(const float4*)&W[XD_OFF + 8]; \
    float4 t3 = *(const float4*)&W[XD_OFF + 12]; \
    float4 t4 = *(const float4*)&W[XD_OFF + 16]; \
    float4 t5 = *(const float4*)&W[XD_OFF + 20]; \
    const float* dtt = ws + OFF_DTT + d; \
    float r0 = dtt[0], r1 = dtt[192], r2 = dtt[384]; \
    float r3 = dtt[576], r4 = dtt[768], r5 = dtt[960]; \
    float d0 = r0 * t0.x, d1 = r0 * t0.y, d2 = r0 * t0.z, d3 = r0 * t0.w; \
    d0 = fmaf(r1, t1.x, d0); d1 = fmaf(r1, t1.y, d1); \
    d2 = fmaf(r1, t1.z, d2); d3 = fmaf(r1, t1.w, d3); \
    d0 = fmaf(r2, t2.x, d0); d1 = fmaf(r2, t2.y, d1); \
    d2 = fmaf(r2, t2.z, d2); d3 = fmaf(r2, t2.w, d3); \
    d0 = fmaf(r3, t3.x, d0); d1 = fmaf(r3, t3.y, d1); \
    d2 = fmaf(r3, t3.z, d2); d3 = fmaf(r3, t3.w, d3); \
    d0 = fmaf(r4, t4.x, d0); d1 = fmaf(r4, t4.y, d1); \
    d2 = fmaf(r4, t4.z, d2); d3 = fmaf(r4, t4.w, d3); \
    d0 = fmaf(r5, t5.x, d0); d1 = fmaf(r5, t5.y, d1); \
    d2 = fmaf(r5, t5.z, d2); d3 = fmaf(r5, t5.w, d3); \
    float bias = b_dt[d]; \
    float dl0 = softplus_f(d0 + bias), dl1 = softplus_f(d1 + bias); \
    float dl2 = softplus_f(d2 + bias), dl3 = softplus_f(d3 + bias); \
    float du0 = dl0 * U4.x, du1 = dl1 * U4.y; \
    float du2 = dl2 * U4.z, du3 = dl3 * U4.w; \
    const float* natp = ws + OFF_NAT + d; \
    float y0 = 0.f, y1 = 0.f, y2 = 0.f, y3 = 0.f; \
    _Pragma("unroll") \
    for (int n = 0; n < NST; ++n) { \
        float an = natp[n * DE]; \
        float4 bn = *(const float4*)&W[XD_OFF + (RNK + n) * 4]; \
        float4 cn = *(const float4*)&W[XD_OFF + (RNK + NST + n) * 4]; \
        float h = du0 * bn.x; \
        y0 = fmaf(h, cn.x, y0); \
        h = fmaf(du1, bn.y, __expf(dl1 * an) * h); \
        y1 = fmaf(h, cn.y, y1); \
        h = fmaf(du2, bn.z, __expf(dl2 * an) * h); \
        y2 = fmaf(h, cn.z, y2); \
        h = fmaf(du3, bn.w, __expf(dl3 * an) * h); \
        y3 = fmaf(h, cn.w, y3); \
    } \
    float Dd = dvec[d]; \
    YOUT.x = fmaf(Dd, U4.x, y0); YOUT.y = fmaf(Dd, U4.y, y1); \
    YOUT.z = fmaf(Dd, U4.z, y2); YOUT.w = fmaf(Dd, U4.w, y3); }
    SCAN_K(0, u0, y_0)
    SCAN_K(1, u1, y_1)
    SCAN_K(2, u2, y_2)
#undef SCAN_K

    // ---------- P-LN: mean/rstd over 192 d per l, via 64-lane butterfly
    float4 mu4, rs4;
    {
        float4 s4, q4;
        s4.x = y_0.x + y_1.x + y_2.x; s4.y = y_0.y + y_1.y + y_2.y;
        s4.z = y_0.z + y_1.z + y_2.z; s4.w = y_0.w + y_1.w + y_2.w;
        q4.x = y_0.x * y_0.x + y_1.x * y_1.x + y_2.x * y_2.x;
        q4.y = y_0.y * y_0.y + y_1.y * y_1.y + y_2.y * y_2.y;
        q4.z = y_0.z * y_0.z + y_1.z * y_1.z + y_2.z * y_2.z;
        q4.w = y_0.w * y_0.w + y_1.w * y_1.w + y_2.w * y_2.w;
        #pragma unroll
        for (int off = 1; off < 64; off <<= 1) {
            s4.x += __shfl_xor(s4.x, off); s4.y += __shfl_xor(s4.y, off);
            s4.z += __shfl_xor(s4.z, off); s4.w += __shfl_xor(s4.w, off);
            q4.x += __shfl_xor(q4.x, off); q4.y += __shfl_xor(q4.y, off);
            q4.z += __shfl_xor(q4.z, off); q4.w += __shfl_xor(q4.w, off);
        }
        const float inv = 1.f / DE;
        mu4.x = s4.x * inv; mu4.y = s4.y * inv;
        mu4.z = s4.z * inv; mu4.w = s4.w * inv;
        rs4.x = rsqrtf(q4.x * inv - mu4.x * mu4.x + 1e-5f);
        rs4.y = rsqrtf(q4.y * inv - mu4.y * mu4.y + 1e-5f);
        rs4.z = rsqrtf(q4.z * inv - mu4.z * mu4.z + 1e-5f);
        rs4.w = rsqrtf(q4.w * inv - mu4.w * mu4.w + 1e-5f);
    }

    // ---------- P-LN2: yz = ((y-mu)*rstd*gamma + beta) * z -> per-wave LDS
#define LN2_K(K, Y4, Z4) { \
    const int d = lane + 64 * (K); \
    float ga = gamma_[d], be = beta_[d]; \
    float4 o; \
    o.x = fmaf((Y4.x - mu4.x) * rs4.x, ga, be) * Z4.x; \
    o.y = fmaf((Y4.y - mu4.y) * rs4.y, ga, be) * Z4.y; \
    o.z = fmaf((Y4.z - mu4.z) * rs4.z, ga, be) * Z4.z; \
    o.w = fmaf((Y4.w - mu4.w) * rs4.w, ga, be) * Z4.w; \
    *(float4*)&W[YZ_OFF + 4 * d] = o; }
    LN2_K(0, y_0, z0)
    LN2_K(1, y_1, z1)
    LN2_K(2, y_2, z2)
#undef LN2_K

    // ---------- P-D: out[dd][l] = sum_d yz[d][l] * wo[d][dd]
    {
        const int dd1 = lane;
        const int dd2 = 64 + (lane & 31);
        const float* wo1 = ws + OFF_WO + dd1;
        const float* wo2 = ws + OFF_WO + dd2;
        float4 o1 = make_float4(0.f, 0.f, 0.f, 0.f);
        float4 o2 = make_float4(0.f, 0.f, 0.f, 0.f);
        #pragma unroll 4
        for (int d = 0; d < DE; ++d) {
            float4 yz = *(const float4*)&W[YZ_OFF + 4 * d];   // b128 broadcast
            float w1 = wo1[d * DM];                           // b32 coalesced
            float w2 = wo2[d * DM];
            o1 = fma4(w1, yz, o1);
            o2 = fma4(w2, yz, o2);
        }
        float* ob = out + (size_t)blk * (SEQ_PB * NJ) + wv * NJ;
        *(float4*)&ob[4 * dd1] = o1;
        if (lane < 32)
            *(float4*)&ob[4 * dd2] = o2;
    }
}

extern "C" void kernel_launch(void* const* d_in, const int* in_sizes, int n_in,
                              void* d_out, int out_size, void* d_ws, size_t ws_size,
                              hipStream_t stream) {
    (void)n_in; (void)ws_size; (void)out_size;
    int nseq = in_sizes[0] / NJ;            // 12544 = 4*56*56
    int grid = nseq / SEQ_PB;               // 3136 blocks
    if (grid < 1) grid = 1;
    float* ws = (float*)d_ws;               // 238 KB used

    prep_weights<<<64, THREADS, 0, stream>>>(
        (const float*)d_in[1],  // in_proj_w
        (const float*)d_in[9],  // out_proj_w
        (const float*)d_in[5],  // A_logs
        (const float*)d_in[3],  // dt_projs_weight
        ws);

    ssm_fused7<<<grid, THREADS, 0, stream>>>(
        (const float*)d_in[0],  // x
        (const float*)d_in[2],  // x_proj_weight
        (const float*)d_in[4],  // dt_projs_bias
        (const float*)d_in[6],  // Ds
        (const float*)d_in[7],  // ln_gamma
        (const float*)d_in[8],  // ln_beta
        ws,
        (float*)d_out);
}